// Round 1
// baseline (1710.156 us; speedup 1.0000x reference)
//
#include <hip/hip_runtime.h>
#include <math.h>
#include <stdint.h>

#define BB 8
#define NCC 6
#define NBOX 900
#define ND 48
#define MTOT (NCC * NBOX * ND)   // 259200 candidates per batch
#define NQ 400
#define REFSZ (BB * NQ * 3)      // 9600 floats, then BB*NQ pad-mask floats

// nan_to_num applied to an f32-rounded double (matches ref's _nan_to_num on the f32 inverse)
__device__ __forceinline__ float nnf(double x) {
    float v = (float)x;
    if (isnan(v)) return 0.0f;
    if (isinf(v)) return v > 0.0f ? 1e6f : -1e6f;
    return v;
}

// ---------------- kernel 0: per-(b,c) K^-1 (3x3) and E^-1 (4x4) ----------------
__global__ void precompute_kernel(const float* __restrict__ K,
                                  const float* __restrict__ E,
                                  float* __restrict__ Kinv,
                                  float* __restrict__ Einv) {
    int t = blockIdx.x * blockDim.x + threadIdx.x;
    if (t >= BB * NCC) return;

    // --- 3x3 inverse of K[:3,:3] via adjugate (double) ---
    const float* Kp = K + t * 16;
    double a00 = Kp[0], a01 = Kp[1], a02 = Kp[2];
    double a10 = Kp[4], a11 = Kp[5], a12 = Kp[6];
    double a20 = Kp[8], a21 = Kp[9], a22 = Kp[10];
    double c00 = a11 * a22 - a12 * a21;
    double c10 = a12 * a20 - a10 * a22;
    double c20 = a10 * a21 - a11 * a20;
    double det = a00 * c00 + a01 * c10 + a02 * c20;
    double id  = 1.0 / det;
    float* Ki = Kinv + t * 9;
    Ki[0] = nnf(c00 * id); Ki[1] = nnf((a02 * a21 - a01 * a22) * id); Ki[2] = nnf((a01 * a12 - a02 * a11) * id);
    Ki[3] = nnf(c10 * id); Ki[4] = nnf((a00 * a22 - a02 * a20) * id); Ki[5] = nnf((a02 * a10 - a00 * a12) * id);
    Ki[6] = nnf(c20 * id); Ki[7] = nnf((a01 * a20 - a00 * a21) * id); Ki[8] = nnf((a00 * a11 - a01 * a10) * id);

    // --- 4x4 inverse of E via Gauss-Jordan with partial pivoting (double) ---
    const float* Ep = E + t * 16;
    double m[4][8];
    for (int i = 0; i < 4; ++i)
        for (int j = 0; j < 4; ++j) {
            m[i][j]     = (double)Ep[i * 4 + j];
            m[i][4 + j] = (i == j) ? 1.0 : 0.0;
        }
    for (int col = 0; col < 4; ++col) {
        int piv = col; double best = fabs(m[col][col]);
        for (int r = col + 1; r < 4; ++r) {
            double v = fabs(m[r][col]);
            if (v > best) { best = v; piv = r; }
        }
        if (piv != col)
            for (int j = 0; j < 8; ++j) { double tmp = m[col][j]; m[col][j] = m[piv][j]; m[piv][j] = tmp; }
        double ipv = 1.0 / m[col][col];
        for (int j = 0; j < 8; ++j) m[col][j] *= ipv;
        for (int r = 0; r < 4; ++r) {
            if (r == col) continue;
            double f = m[r][col];
            if (f != 0.0)
                for (int j = 0; j < 8; ++j) m[r][j] -= f * m[col][j];
        }
    }
    float* Ei = Einv + t * 16;
    for (int i = 0; i < 4; ++i)
        for (int j = 0; j < 4; ++j) Ei[i * 4 + j] = nnf(m[i][4 + j]);
}

// ---------------- kernel 1: per-candidate mask + area key ----------------
// area_bits[b*MTOT + m] = float bits of area if masked else 0 (area > 5 so bits != 0)
__global__ __launch_bounds__(256) void mask_kernel(const float* __restrict__ boxes,
                                                   const float* __restrict__ K,
                                                   const float* __restrict__ E,
                                                   const float* __restrict__ Kinv,
                                                   const float* __restrict__ Einv,
                                                   uint32_t* __restrict__ area_bits) {
    int idx = blockIdx.x * blockDim.x + threadIdx.x;
    if (idx >= BB * MTOT) return;
    int b  = idx / MTOT;
    int m  = idx - b * MTOT;           // m = (c*NBOX + n)*ND + d  (reference flat index)
    int d  = m % ND;
    int cn = m / ND;                   // c*NBOX + n
    int bc = b * NCC + cn / NBOX;

    const float* box = boxes + (b * NCC * NBOX + cn) * 4;
    float x1 = box[0], y1 = box[1], x2 = box[2], y2 = box[3];
    float area  = (x2 - x1) * (y2 - y1);
    bool  valid = (area > 5.0f) && (area < 197120.0f);   // 800*448*0.55

    float cx = (x1 + x2) * 0.5f, cy = (y1 + y2) * 0.5f;
    const float step = (60.0f - 1.0f) / 47.0f;
    float z = (d == ND - 1) ? 60.0f : 1.0f + (float)d * step;

    const float* Ki = Kinv + bc * 9;
    float u0 = cx * z, u1 = cy * z;
    float pcx = Ki[0] * u0 + Ki[1] * u1 + Ki[2] * z;
    float pcy = Ki[3] * u0 + Ki[4] * u1 + Ki[5] * z;
    float pcz = Ki[6] * u0 + Ki[7] * u1 + Ki[8] * z;

    const float* Ep = E + bc * 16;
    float X = Ep[0] * pcx + Ep[1] * pcy + Ep[2]  * pcz + Ep[3];
    float Y = Ep[4] * pcx + Ep[5] * pcy + Ep[6]  * pcz + Ep[7];
    float Z = Ep[8] * pcx + Ep[9] * pcy + Ep[10] * pcz + Ep[11];

    const float* Ev = Einv + bc * 16;
    float q0 = Ev[0]  * X + Ev[1]  * Y + Ev[2]  * Z + Ev[3];
    float q1 = Ev[4]  * X + Ev[5]  * Y + Ev[6]  * Z + Ev[7];
    float q2 = Ev[8]  * X + Ev[9]  * Y + Ev[10] * Z + Ev[11];
    float q3 = Ev[12] * X + Ev[13] * Y + Ev[14] * Z + Ev[15];
    float w  = q3 + 1e-6f;
    float r0 = q0 / w, r1 = q1 / w, r2 = q2 / w;

    const float* Kp = K + bc * 16;
    float p0 = Kp[0] * r0 + Kp[1] * r1 + Kp[2]  * r2;
    float p1 = Kp[4] * r0 + Kp[5] * r1 + Kp[6]  * r2;
    float p2 = Kp[8] * r0 + Kp[9] * r1 + Kp[10] * r2;
    float iz = p2 + 1e-6f;
    float ix = p0 / iz, iy = p1 / iz;

    float bs = 40.0f * (10.0f / (r2 + 1e-6f));
    bs = fminf(fmaxf(bs, 8.0f), 200.0f);
    float h = bs / 2.0f;
    float px1 = ix - h, py1 = iy - h, px2 = ix + h, py2 = iy + h;

    float ix1 = fmaxf(px1, x1), iy1 = fmaxf(py1, y1);
    float ix2 = fminf(px2, x2), iy2 = fminf(py2, y2);
    float inter = fmaxf(ix2 - ix1, 0.0f) * fmaxf(iy2 - iy1, 0.0f);
    float a1 = (px2 - px1) * (py2 - py1);
    float a2 = (x2 - x1) * (y2 - y1);
    float iou = inter / (a1 + a2 - inter + 1e-6f);

    bool masked = (iou > 0.05f) && valid;
    area_bits[idx] = masked ? __float_as_uint(area) : 0u;
}

// ---------------- kernel 2: per-batch top-400 select + output ----------------
// key (distinct per candidate):
//   count > 400 : (area_bits << 32) | (0xFFFFFFFF - m)   -> area desc, index asc
//   count <= 400: (1 << 32)        | (0xFFFFFFFF - m)   -> index asc
__global__ __launch_bounds__(256) void select_kernel(const uint32_t* __restrict__ area_bits,
                                                     const float* __restrict__ boxes,
                                                     const float* __restrict__ E,
                                                     const float* __restrict__ Kinv,
                                                     float* __restrict__ out) {
    int b   = blockIdx.x;
    int tid = threadIdx.x;
    const uint32_t* ab = area_bits + b * MTOT;

    __shared__ unsigned long long skeys[512];
    __shared__ int hist[256];
    __shared__ unsigned long long s_prefix;
    __shared__ int s_need;
    __shared__ int s_done;
    __shared__ int s_cnt;

    // ---- phase 0: count masked ----
    int local = 0;
    for (int m = tid; m < MTOT; m += 256) local += (ab[m] != 0u);
    hist[tid] = local;
    __syncthreads();
    for (int s = 128; s > 0; s >>= 1) {
        if (tid < s) hist[tid] += hist[tid + s];
        __syncthreads();
    }
    int count = hist[0];
    __syncthreads();
    bool regime_area = count > NQ;
    int Ksel = count < NQ ? count : NQ;

    // ---- phase 1: radix-select threshold T = Ksel-th largest key ----
    unsigned long long T = 0;
    if (Ksel > 0) {
        if (tid == 0) { s_prefix = 0ull; s_need = Ksel; s_done = 0; }
        for (int shift = 56; shift >= 0; shift -= 8) {
            hist[tid] = 0;
            __syncthreads();
            unsigned long long pref = s_prefix;
            for (int m = tid; m < MTOT; m += 256) {
                uint32_t abv = ab[m];
                if (!abv) continue;
                unsigned long long k = regime_area
                    ? (((unsigned long long)abv << 32) | (unsigned long long)(0xFFFFFFFFu - (uint32_t)m))
                    : ((1ull << 32) | (unsigned long long)(0xFFFFFFFFu - (uint32_t)m));
                bool match = (shift == 56) || ((k >> (shift + 8)) == (pref >> (shift + 8)));
                if (match) atomicAdd(&hist[(int)((k >> shift) & 255ull)], 1);
            }
            __syncthreads();
            if (tid == 0) {
                int need = s_need, cum = 0, dsel = 0;
                for (int dg = 255; dg >= 0; --dg) {
                    int hc = hist[dg];
                    if (cum + hc >= need) {
                        dsel = dg;
                        s_need = need - cum;
                        if (hc == need - cum) s_done = 1;  // bin exactly covers remainder
                        break;
                    }
                    cum += hc;
                }
                s_prefix = pref | ((unsigned long long)dsel << shift);
            }
            __syncthreads();
            if (s_done) break;
        }
        T = s_prefix;

        // ---- phase 2: collect the Ksel keys >= T ----
        if (tid == 0) s_cnt = 0;
        __syncthreads();
        for (int m = tid; m < MTOT; m += 256) {
            uint32_t abv = ab[m];
            if (!abv) continue;
            unsigned long long k = regime_area
                ? (((unsigned long long)abv << 32) | (unsigned long long)(0xFFFFFFFFu - (uint32_t)m))
                : ((1ull << 32) | (unsigned long long)(0xFFFFFFFFu - (uint32_t)m));
            if (k >= T) {
                int p = atomicAdd(&s_cnt, 1);
                if (p < 512) skeys[p] = k;
            }
        }
        __syncthreads();
    }
    // pad unused slots
    for (int i = tid; i < 512; i += 256)
        if (i >= Ksel) skeys[i] = 0ull;
    __syncthreads();

    // ---- phase 3: bitonic sort 512 ascending (rank j largest at [511-j]) ----
    for (int kk = 2; kk <= 512; kk <<= 1) {
        for (int j = kk >> 1; j > 0; j >>= 1) {
            for (int i = tid; i < 512; i += 256) {
                int ixj = i ^ j;
                if (ixj > i) {
                    bool up = ((i & kk) == 0);
                    unsigned long long av = skeys[i], bv = skeys[ixj];
                    if ((av > bv) == up) { skeys[i] = bv; skeys[ixj] = av; }
                }
            }
            __syncthreads();
        }
    }

    // ---- phase 4: recompute points_3d for selected, write outputs ----
    const float denom = 102.4f + 1e-6f;   // SR_MAX-SR_MIN+1e-6 in f32
    for (int q = tid; q < NQ; q += 256) {
        float X = 0.0f, Y = 0.0f, Z = 0.0f, pm = 1.0f;
        if (q < Ksel) {
            unsigned long long k = skeys[511 - q];
            uint32_t mm = 0xFFFFFFFFu - (uint32_t)(k & 0xFFFFFFFFull);
            int d  = (int)(mm % ND);
            int cn = (int)(mm / ND);
            int bc = b * NCC + cn / NBOX;
            const float* box = boxes + (b * NCC * NBOX + cn) * 4;
            float x1 = box[0], y1 = box[1], x2 = box[2], y2 = box[3];
            float cx = (x1 + x2) * 0.5f, cy = (y1 + y2) * 0.5f;
            const float step = (60.0f - 1.0f) / 47.0f;
            float z = (d == ND - 1) ? 60.0f : 1.0f + (float)d * step;
            const float* Ki = Kinv + bc * 9;
            float u0 = cx * z, u1 = cy * z;
            float pcx = Ki[0] * u0 + Ki[1] * u1 + Ki[2] * z;
            float pcy = Ki[3] * u0 + Ki[4] * u1 + Ki[5] * z;
            float pcz = Ki[6] * u0 + Ki[7] * u1 + Ki[8] * z;
            const float* Ep = E + bc * 16;
            X = Ep[0] * pcx + Ep[1] * pcy + Ep[2]  * pcz + Ep[3];
            Y = Ep[4] * pcx + Ep[5] * pcy + Ep[6]  * pcz + Ep[7];
            Z = Ep[8] * pcx + Ep[9] * pcy + Ep[10] * pcz + Ep[11];
            pm = 0.0f;
        }
        float* o = out + (b * NQ + q) * 3;
        o[0] = fminf(fmaxf((X + 51.2f) / denom, 0.0f), 1.0f);
        o[1] = fminf(fmaxf((Y + 51.2f) / denom, 0.0f), 1.0f);
        o[2] = fminf(fmaxf((Z + 51.2f) / denom, 0.0f), 1.0f);
        out[REFSZ + b * NQ + q] = pm;
    }
}

extern "C" void kernel_launch(void* const* d_in, const int* in_sizes, int n_in,
                              void* d_out, int out_size, void* d_ws, size_t ws_size,
                              hipStream_t stream) {
    const float* boxes = (const float*)d_in[0];
    const float* K     = (const float*)d_in[1];
    const float* E     = (const float*)d_in[2];
    // ws layout: [0,2048) Kinv (48*9 f32) | [2048,8192) Einv (48*16 f32) | [8192,..) area_bits
    float*    Kinv      = (float*)d_ws;
    float*    Einv      = (float*)((char*)d_ws + 2048);
    uint32_t* area_bits = (uint32_t*)((char*)d_ws + 8192);
    float*    out       = (float*)d_out;

    precompute_kernel<<<1, 64, 0, stream>>>(K, E, Kinv, Einv);
    int total = BB * MTOT;
    mask_kernel<<<(total + 255) / 256, 256, 0, stream>>>(boxes, K, E, Kinv, Einv, area_bits);
    select_kernel<<<BB, 256, 0, stream>>>(area_bits, boxes, E, Kinv, out);
}

// Round 2
// 257.133 us; speedup vs baseline: 6.6509x; 6.6509x over previous
//
#include <hip/hip_runtime.h>
#include <math.h>
#include <stdint.h>

#define BB 8
#define NCC 6
#define NBOX 900
#define NBOXES (NCC * NBOX)      // 5400 boxes per batch
#define ND 48
#define NQ 400
#define REFSZ (BB * NQ * 3)      // 9600 floats, then BB*NQ pad-mask floats
#define SORTN 8192               // bitonic size >= NBOXES

// nan_to_num applied to an f32-rounded double (matches ref's _nan_to_num on the f32 inverse)
__device__ __forceinline__ float nnf(double x) {
    float v = (float)x;
    if (isnan(v)) return 0.0f;
    if (isinf(v)) return v > 0.0f ? 1e6f : -1e6f;
    return v;
}

// ---------------- kernel 0: per-(b,c) K^-1 (3x3) and E^-1 (4x4) ----------------
__global__ void precompute_kernel(const float* __restrict__ K,
                                  const float* __restrict__ E,
                                  float* __restrict__ Kinv,
                                  float* __restrict__ Einv) {
    int t = blockIdx.x * blockDim.x + threadIdx.x;
    if (t >= BB * NCC) return;

    const float* Kp = K + t * 16;
    double a00 = Kp[0], a01 = Kp[1], a02 = Kp[2];
    double a10 = Kp[4], a11 = Kp[5], a12 = Kp[6];
    double a20 = Kp[8], a21 = Kp[9], a22 = Kp[10];
    double c00 = a11 * a22 - a12 * a21;
    double c10 = a12 * a20 - a10 * a22;
    double c20 = a10 * a21 - a11 * a20;
    double det = a00 * c00 + a01 * c10 + a02 * c20;
    double id  = 1.0 / det;
    float* Ki = Kinv + t * 9;
    Ki[0] = nnf(c00 * id); Ki[1] = nnf((a02 * a21 - a01 * a22) * id); Ki[2] = nnf((a01 * a12 - a02 * a11) * id);
    Ki[3] = nnf(c10 * id); Ki[4] = nnf((a00 * a22 - a02 * a20) * id); Ki[5] = nnf((a02 * a10 - a00 * a12) * id);
    Ki[6] = nnf(c20 * id); Ki[7] = nnf((a01 * a20 - a00 * a21) * id); Ki[8] = nnf((a00 * a11 - a01 * a10) * id);

    const float* Ep = E + t * 16;
    double m[4][8];
    for (int i = 0; i < 4; ++i)
        for (int j = 0; j < 4; ++j) {
            m[i][j]     = (double)Ep[i * 4 + j];
            m[i][4 + j] = (i == j) ? 1.0 : 0.0;
        }
    for (int col = 0; col < 4; ++col) {
        int piv = col; double best = fabs(m[col][col]);
        for (int r = col + 1; r < 4; ++r) {
            double v = fabs(m[r][col]);
            if (v > best) { best = v; piv = r; }
        }
        if (piv != col)
            for (int j = 0; j < 8; ++j) { double tmp = m[col][j]; m[col][j] = m[piv][j]; m[piv][j] = tmp; }
        double ipv = 1.0 / m[col][col];
        for (int j = 0; j < 8; ++j) m[col][j] *= ipv;
        for (int r = 0; r < 4; ++r) {
            if (r == col) continue;
            double f = m[r][col];
            if (f != 0.0)
                for (int j = 0; j < 8; ++j) m[r][j] -= f * m[col][j];
        }
    }
    float* Ei = Einv + t * 16;
    for (int i = 0; i < 4; ++i)
        for (int j = 0; j < 4; ++j) Ei[i * 4 + j] = nnf(m[i][4 + j]);
}

// ---------------- kernel 1: per-box mask over 48 depths ----------------
// One thread per (b, box). Writes a 48-bit depth mask (u64) and the box area bits.
__global__ __launch_bounds__(256) void mask_box_kernel(const float* __restrict__ boxes,
                                                       const float* __restrict__ K,
                                                       const float* __restrict__ E,
                                                       const float* __restrict__ Kinv,
                                                       const float* __restrict__ Einv,
                                                       uint64_t* __restrict__ mask64,
                                                       uint32_t* __restrict__ area_bits) {
    int idx = blockIdx.x * blockDim.x + threadIdx.x;
    if (idx >= BB * NBOXES) return;
    int b  = idx / NBOXES;
    int cn = idx - b * NBOXES;         // c*NBOX + n
    int bc = b * NCC + cn / NBOX;

    const float* box = boxes + idx * 4;
    float x1 = box[0], y1 = box[1], x2 = box[2], y2 = box[3];
    float area  = (x2 - x1) * (y2 - y1);
    bool  valid = (area > 5.0f) && (area < 197120.0f);   // 800*448*0.55
    area_bits[idx] = __float_as_uint(area);

    uint64_t mask = 0;
    if (valid) {
        float cx = (x1 + x2) * 0.5f, cy = (y1 + y2) * 0.5f;
        const float step = (60.0f - 1.0f) / 47.0f;

        // hoist matrices into registers
        const float* Kip = Kinv + bc * 9;
        float Ki[9];
        #pragma unroll
        for (int i = 0; i < 9; ++i) Ki[i] = Kip[i];
        const float* Epp = E + bc * 16;
        float Ep[12];
        #pragma unroll
        for (int i = 0; i < 12; ++i) Ep[i] = Epp[i];
        const float* Evp = Einv + bc * 16;
        float Ev[16];
        #pragma unroll
        for (int i = 0; i < 16; ++i) Ev[i] = Evp[i];
        const float* Kpp = K + bc * 16;
        float Kp[11];
        #pragma unroll
        for (int i = 0; i < 11; ++i) Kp[i] = Kpp[i];

        for (int d = 0; d < ND; ++d) {
            float z = (d == ND - 1) ? 60.0f : 1.0f + (float)d * step;
            float u0 = cx * z, u1 = cy * z;
            float pcx = Ki[0] * u0 + Ki[1] * u1 + Ki[2] * z;
            float pcy = Ki[3] * u0 + Ki[4] * u1 + Ki[5] * z;
            float pcz = Ki[6] * u0 + Ki[7] * u1 + Ki[8] * z;

            float X = Ep[0] * pcx + Ep[1] * pcy + Ep[2]  * pcz + Ep[3];
            float Y = Ep[4] * pcx + Ep[5] * pcy + Ep[6]  * pcz + Ep[7];
            float Z = Ep[8] * pcx + Ep[9] * pcy + Ep[10] * pcz + Ep[11];

            float q0 = Ev[0]  * X + Ev[1]  * Y + Ev[2]  * Z + Ev[3];
            float q1 = Ev[4]  * X + Ev[5]  * Y + Ev[6]  * Z + Ev[7];
            float q2 = Ev[8]  * X + Ev[9]  * Y + Ev[10] * Z + Ev[11];
            float q3 = Ev[12] * X + Ev[13] * Y + Ev[14] * Z + Ev[15];
            float w  = q3 + 1e-6f;
            float r0 = q0 / w, r1 = q1 / w, r2 = q2 / w;

            float p0 = Kp[0] * r0 + Kp[1] * r1 + Kp[2]  * r2;
            float p1 = Kp[4] * r0 + Kp[5] * r1 + Kp[6]  * r2;
            float p2 = Kp[8] * r0 + Kp[9] * r1 + Kp[10] * r2;
            float iz = p2 + 1e-6f;
            float ix = p0 / iz, iy = p1 / iz;

            float bs = 40.0f * (10.0f / (r2 + 1e-6f));
            bs = fminf(fmaxf(bs, 8.0f), 200.0f);
            float hh = bs / 2.0f;
            float px1 = ix - hh, py1 = iy - hh, px2 = ix + hh, py2 = iy + hh;

            float ix1 = fmaxf(px1, x1), iy1 = fmaxf(py1, y1);
            float ix2 = fminf(px2, x2), iy2 = fminf(py2, y2);
            float inter = fmaxf(ix2 - ix1, 0.0f) * fmaxf(iy2 - iy1, 0.0f);
            float a1 = (px2 - px1) * (py2 - py1);
            float iou = inter / (a1 + area - inter + 1e-6f);

            if (iou > 0.05f) mask |= (1ull << d);
        }
    }
    mask64[idx] = mask;
}

// ---------------- kernel 2: per-batch top-400 select + output ----------------
// Box-level keys (distinct per box):
//   area regime (count > 400): (area_bits << 32) | (inv_box << 6) | cnt
//   order regime (count <= 400): (1 << 32) | (inv_box << 6) | cnt
// Sorting descending gives exactly the reference candidate order at box
// granularity; within a box, masked depths ascend (= candidate index ascend).
__global__ __launch_bounds__(512) void select_kernel(const uint64_t* __restrict__ mask64,
                                                     const uint32_t* __restrict__ area_bits,
                                                     const float* __restrict__ boxes,
                                                     const float* __restrict__ E,
                                                     const float* __restrict__ Kinv,
                                                     float* __restrict__ out) {
    int b   = blockIdx.x;
    int tid = threadIdx.x;
    const uint64_t* mb = mask64 + b * NBOXES;
    const uint32_t* ab = area_bits + b * NBOXES;

    __shared__ uint64_t s_keys[SORTN];      // 64 KB
    __shared__ int      s_scan[512];
    __shared__ int      s_box[512];
    __shared__ int      s_start[512];
    __shared__ int      s_total;

    // ---- phase 0: build keys + count total masked ----
    int partial = 0;
    for (int t = tid; t < SORTN; t += 512) {
        uint64_t key = 0;
        if (t < NBOXES) {
            uint64_t mask = mb[t];
            int cnt = __builtin_popcountll(mask);
            partial += cnt;
            if (cnt > 0) {
                uint64_t inv = (uint64_t)(SORTN - 1 - t);   // 13 bits, descending in box
                key = ((uint64_t)ab[t] << 32) | (inv << 6) | (uint64_t)cnt;
            }
        }
        s_keys[t] = key;
    }
    s_scan[tid] = partial;
    __syncthreads();
    for (int s = 256; s > 0; s >>= 1) {
        if (tid < s) s_scan[tid] += s_scan[tid + s];
        __syncthreads();
    }
    if (tid == 0) s_total = s_scan[0];
    __syncthreads();
    int total = s_total;
    bool regime_area = total > NQ;
    int total_take = total < NQ ? total : NQ;

    // ---- phase 1: order regime -> rewrite keys so sort yields box-ascending ----
    if (!regime_area) {
        for (int t = tid; t < NBOXES; t += 512) {
            uint64_t key = s_keys[t];
            if (key) s_keys[t] = (1ull << 32) | (key & 0x7FFFFull);
        }
        __syncthreads();
    }

    // ---- phase 2: bitonic sort SORTN ascending (largest at the top) ----
    for (int kk = 2; kk <= SORTN; kk <<= 1) {
        for (int j = kk >> 1; j > 0; j >>= 1) {
            for (int i = tid; i < SORTN; i += 512) {
                int ixj = i ^ j;
                if (ixj > i) {
                    bool up = ((i & kk) == 0);
                    uint64_t av = s_keys[i], bv = s_keys[ixj];
                    if ((av > bv) == up) { s_keys[i] = bv; s_keys[ixj] = av; }
                }
            }
            __syncthreads();
        }
    }

    // ---- phase 3: exclusive prefix of counts over the top-512 sorted boxes ----
    // (<=400 boxes can ever be selected since each contributes >=1 candidate)
    uint64_t mykey = s_keys[SORTN - 1 - tid];
    int mycnt = (int)(mykey & 63ull);
    s_scan[tid] = mycnt;
    __syncthreads();
    for (int off = 1; off < 512; off <<= 1) {
        int v = (tid >= off) ? s_scan[tid - off] : 0;
        __syncthreads();
        s_scan[tid] += v;
        __syncthreads();
    }
    int excl = s_scan[tid] - mycnt;
    s_start[tid] = (mycnt > 0) ? excl : 0x7FFFFFFF;
    s_box[tid]   = (SORTN - 1) - (int)((mykey >> 6) & (uint64_t)(SORTN - 1));
    __syncthreads();

    // ---- phase 4: emit 400 outputs ----
    const float denom = 102.4f + 1e-6f;   // SR_MAX-SR_MIN+1e-6 in f32
    for (int q = tid; q < NQ; q += 512) {
        float X = 0.0f, Y = 0.0f, Z = 0.0f, pm = 1.0f;
        if (q < total_take) {
            // largest i with s_start[i] <= q
            int lo = 0, hi = 511;
            while (lo < hi) {
                int mid = (lo + hi + 1) >> 1;
                if (s_start[mid] <= q) lo = mid; else hi = mid - 1;
            }
            int cn = s_box[lo];
            int r  = q - s_start[lo];
            uint64_t mask = mb[cn];
            for (int j = 0; j < r; ++j) mask &= (mask - 1);
            int d = __builtin_ctzll(mask);

            int bc = b * NCC + cn / NBOX;
            const float* box = boxes + (b * NBOXES + cn) * 4;
            float x1 = box[0], y1 = box[1], x2 = box[2], y2 = box[3];
            float cx = (x1 + x2) * 0.5f, cy = (y1 + y2) * 0.5f;
            const float step = (60.0f - 1.0f) / 47.0f;
            float z = (d == ND - 1) ? 60.0f : 1.0f + (float)d * step;
            const float* Ki = Kinv + bc * 9;
            float u0 = cx * z, u1 = cy * z;
            float pcx = Ki[0] * u0 + Ki[1] * u1 + Ki[2] * z;
            float pcy = Ki[3] * u0 + Ki[4] * u1 + Ki[5] * z;
            float pcz = Ki[6] * u0 + Ki[7] * u1 + Ki[8] * z;
            const float* Ep = E + bc * 16;
            X = Ep[0] * pcx + Ep[1] * pcy + Ep[2]  * pcz + Ep[3];
            Y = Ep[4] * pcx + Ep[5] * pcy + Ep[6]  * pcz + Ep[7];
            Z = Ep[8] * pcx + Ep[9] * pcy + Ep[10] * pcz + Ep[11];
            pm = 0.0f;
        }
        float* o = out + (b * NQ + q) * 3;
        o[0] = fminf(fmaxf((X + 51.2f) / denom, 0.0f), 1.0f);
        o[1] = fminf(fmaxf((Y + 51.2f) / denom, 0.0f), 1.0f);
        o[2] = fminf(fmaxf((Z + 51.2f) / denom, 0.0f), 1.0f);
        out[REFSZ + b * NQ + q] = pm;
    }
}

extern "C" void kernel_launch(void* const* d_in, const int* in_sizes, int n_in,
                              void* d_out, int out_size, void* d_ws, size_t ws_size,
                              hipStream_t stream) {
    const float* boxes = (const float*)d_in[0];
    const float* K     = (const float*)d_in[1];
    const float* E     = (const float*)d_in[2];
    // ws layout: [0,4096) Kinv (48*9 f32) | [4096,8192) Einv (48*16 f32)
    //            [8192, 8192+172800) area_bits (8*5400 u32)
    //            [180992, 180992+345600) mask64 (8*5400 u64)
    float*    Kinv      = (float*)d_ws;
    float*    Einv      = (float*)((char*)d_ws + 4096);
    uint32_t* area_bits = (uint32_t*)((char*)d_ws + 8192);
    uint64_t* mask64    = (uint64_t*)((char*)d_ws + 180992);
    float*    out       = (float*)d_out;

    precompute_kernel<<<1, 64, 0, stream>>>(K, E, Kinv, Einv);
    int nbox_total = BB * NBOXES;
    mask_box_kernel<<<(nbox_total + 255) / 256, 256, 0, stream>>>(
        boxes, K, E, Kinv, Einv, mask64, area_bits);
    select_kernel<<<BB, 512, 0, stream>>>(mask64, area_bits, boxes, E, Kinv, out);
}

// Round 3
// 236.097 us; speedup vs baseline: 7.2434x; 1.0891x over previous
//
#include <hip/hip_runtime.h>
#include <math.h>
#include <stdint.h>

#define BB 8
#define NCC 6
#define NBOX 900
#define NBOXES (NCC * NBOX)      // 5400 boxes per batch
#define NBC (BB * NCC)           // 48 cameras
#define ND 48
#define TPB_BOX 6                // threads per box in mask kernel (8 depths each)
#define NQ 400
#define REFSZ (BB * NQ * 3)
#define NPAD 5408                // padded box count (multiple-friendly, 13-bit inv fits)

// nan_to_num applied to an f32-rounded double (matches ref's _nan_to_num on the f32 inverse)
__device__ __forceinline__ float nnf(double x) {
    float v = (float)x;
    if (isnan(v)) return 0.0f;
    if (isinf(v)) return v > 0.0f ? 1e6f : -1e6f;
    return v;
}

// 3x3 inverse of K[:3,:3] via adjugate in double, rounded to f32 + nan_to_num
__device__ void invert3x3(const float* __restrict__ Kp, float* __restrict__ Ki) {
    double a00 = Kp[0], a01 = Kp[1], a02 = Kp[2];
    double a10 = Kp[4], a11 = Kp[5], a12 = Kp[6];
    double a20 = Kp[8], a21 = Kp[9], a22 = Kp[10];
    double c00 = a11 * a22 - a12 * a21;
    double c10 = a12 * a20 - a10 * a22;
    double c20 = a10 * a21 - a11 * a20;
    double det = a00 * c00 + a01 * c10 + a02 * c20;
    double id  = 1.0 / det;
    Ki[0] = nnf(c00 * id); Ki[1] = nnf((a02 * a21 - a01 * a22) * id); Ki[2] = nnf((a01 * a12 - a02 * a11) * id);
    Ki[3] = nnf(c10 * id); Ki[4] = nnf((a00 * a22 - a02 * a20) * id); Ki[5] = nnf((a02 * a10 - a00 * a12) * id);
    Ki[6] = nnf(c20 * id); Ki[7] = nnf((a01 * a20 - a00 * a21) * id); Ki[8] = nnf((a00 * a11 - a01 * a10) * id);
}

// 4x4 inverse via Gauss-Jordan with partial pivoting in double, rounded + nan_to_num
__device__ void invert4x4(const float* __restrict__ Ep, float* __restrict__ Ei) {
    double m[4][8];
    for (int i = 0; i < 4; ++i)
        for (int j = 0; j < 4; ++j) {
            m[i][j]     = (double)Ep[i * 4 + j];
            m[i][4 + j] = (i == j) ? 1.0 : 0.0;
        }
    for (int col = 0; col < 4; ++col) {
        int piv = col; double best = fabs(m[col][col]);
        for (int r = col + 1; r < 4; ++r) {
            double v = fabs(m[r][col]);
            if (v > best) { best = v; piv = r; }
        }
        if (piv != col)
            for (int j = 0; j < 8; ++j) { double tmp = m[col][j]; m[col][j] = m[piv][j]; m[piv][j] = tmp; }
        double ipv = 1.0 / m[col][col];
        for (int j = 0; j < 8; ++j) m[col][j] *= ipv;
        for (int r = 0; r < 4; ++r) {
            if (r == col) continue;
            double f = m[r][col];
            if (f != 0.0)
                for (int j = 0; j < 8; ++j) m[r][j] -= f * m[col][j];
        }
    }
    for (int i = 0; i < 16; ++i) Ei[i] = nnf(m[i / 4][4 + (i & 3)]);
}

// ---------------- kernel 1: per-(box, j) mask over 8 depths ----------------
// 6 threads per box; thread j writes byte j of the box's u64 depth mask
// (bits j*8 .. j*8+7). j==0 also writes area_bits and zeroes mask bytes 6-7.
// Each block computes the <=2 needed (Kinv, Einv) pairs into LDS (fused precompute).
__global__ __launch_bounds__(256) void mask_kernel(const float* __restrict__ boxes,
                                                   const float* __restrict__ K,
                                                   const float* __restrict__ E,
                                                   uint8_t* __restrict__ mask_bytes,
                                                   uint32_t* __restrict__ area_bits) {
    __shared__ float sKi[2][9];
    __shared__ float sEv[2][16];

    int gbase = blockIdx.x * 256;
    int bc_lo = gbase / (NBOX * TPB_BOX);                       // = gtid/5400
    int bc_hi = (gbase + 255) / (NBOX * TPB_BOX);
    if (bc_hi > NBC - 1) bc_hi = NBC - 1;
    if (threadIdx.x == 0) {
        invert3x3(K + bc_lo * 16, sKi[0]);
        invert4x4(E + bc_lo * 16, sEv[0]);
    }
    if (threadIdx.x == 1 && bc_hi != bc_lo) {
        invert3x3(K + bc_hi * 16, sKi[1]);
        invert4x4(E + bc_hi * 16, sEv[1]);
    }
    __syncthreads();

    int gtid = gbase + threadIdx.x;
    if (gtid >= BB * NBOXES * TPB_BOX) return;
    int box = gtid / TPB_BOX;            // global box index: b*NBOXES + cn
    int j   = gtid - box * TPB_BOX;      // 0..5
    int bc  = box / NBOX;                // = b*NCC + c

    const float* bx = boxes + box * 4;
    float x1 = bx[0], y1 = bx[1], x2 = bx[2], y2 = bx[3];
    float area  = (x2 - x1) * (y2 - y1);
    bool  valid = (area > 5.0f) && (area < 197120.0f);   // 800*448*0.55
    if (j == 0) {
        area_bits[box] = __float_as_uint(area);
        *(uint16_t*)(mask_bytes + box * 8 + 6) = 0;      // zero mask bytes 6,7
    }

    uint32_t m8 = 0;
    if (valid) {
        int sel = (bc == bc_lo) ? 0 : 1;
        float Ki[9], Ev[16], Ep[12], Kp[11];
        #pragma unroll
        for (int i = 0; i < 9; ++i)  Ki[i] = sKi[sel][i];
        #pragma unroll
        for (int i = 0; i < 16; ++i) Ev[i] = sEv[sel][i];
        const float* Epp = E + bc * 16;
        #pragma unroll
        for (int i = 0; i < 12; ++i) Ep[i] = Epp[i];
        const float* Kpp = K + bc * 16;
        #pragma unroll
        for (int i = 0; i < 11; ++i) Kp[i] = Kpp[i];

        float cx = (x1 + x2) * 0.5f, cy = (y1 + y2) * 0.5f;
        const float step = (60.0f - 1.0f) / 47.0f;

        #pragma unroll
        for (int dd = 0; dd < 8; ++dd) {
            int d = j * 8 + dd;
            float z = (d == ND - 1) ? 60.0f : 1.0f + (float)d * step;
            float u0 = cx * z, u1 = cy * z;
            float pcx = Ki[0] * u0 + Ki[1] * u1 + Ki[2] * z;
            float pcy = Ki[3] * u0 + Ki[4] * u1 + Ki[5] * z;
            float pcz = Ki[6] * u0 + Ki[7] * u1 + Ki[8] * z;

            float X = Ep[0] * pcx + Ep[1] * pcy + Ep[2]  * pcz + Ep[3];
            float Y = Ep[4] * pcx + Ep[5] * pcy + Ep[6]  * pcz + Ep[7];
            float Z = Ep[8] * pcx + Ep[9] * pcy + Ep[10] * pcz + Ep[11];

            float q0 = Ev[0]  * X + Ev[1]  * Y + Ev[2]  * Z + Ev[3];
            float q1 = Ev[4]  * X + Ev[5]  * Y + Ev[6]  * Z + Ev[7];
            float q2 = Ev[8]  * X + Ev[9]  * Y + Ev[10] * Z + Ev[11];
            float q3 = Ev[12] * X + Ev[13] * Y + Ev[14] * Z + Ev[15];
            float w  = q3 + 1e-6f;
            float r0 = q0 / w, r1 = q1 / w, r2 = q2 / w;

            float p0 = Kp[0] * r0 + Kp[1] * r1 + Kp[2]  * r2;
            float p1 = Kp[4] * r0 + Kp[5] * r1 + Kp[6]  * r2;
            float p2 = Kp[8] * r0 + Kp[9] * r1 + Kp[10] * r2;
            float iz = p2 + 1e-6f;
            float ix = p0 / iz, iy = p1 / iz;

            float bs = 40.0f * (10.0f / (r2 + 1e-6f));
            bs = fminf(fmaxf(bs, 8.0f), 200.0f);
            float hh = bs / 2.0f;
            float px1 = ix - hh, py1 = iy - hh, px2 = ix + hh, py2 = iy + hh;

            float ix1 = fmaxf(px1, x1), iy1 = fmaxf(py1, y1);
            float ix2 = fminf(px2, x2), iy2 = fminf(py2, y2);
            float inter = fmaxf(ix2 - ix1, 0.0f) * fmaxf(iy2 - iy1, 0.0f);
            float a1 = (px2 - px1) * (py2 - py1);
            float iou = inter / (a1 + area - inter + 1e-6f);

            if (iou > 0.05f) m8 |= (1u << dd);
        }
    }
    mask_bytes[box * 8 + j] = (uint8_t)m8;
}

// ---------------- kernel 2: per-batch top-400 select + output ----------------
// Box key: (area_bits << 32) | (inv_box << 6) | cnt   (distinct; sorts by
// area desc then box asc; cnt rides in the low bits as the radix weight).
// Area regime (total > 400): weighted radix-select the boundary key, compact
// the <=400 surviving boxes, bitonic-sort 512, prefix counts, emit.
// Order regime (total <= 400): blocked prefix over boxes in index order, emit.
__global__ __launch_bounds__(512) void select_kernel(const uint64_t* __restrict__ mask64,
                                                     const uint32_t* __restrict__ area_bits,
                                                     const float* __restrict__ boxes,
                                                     const float* __restrict__ K,
                                                     const float* __restrict__ E,
                                                     float* __restrict__ out) {
    int b   = blockIdx.x;
    int tid = threadIdx.x;
    const uint64_t* mb = mask64 + b * NBOXES;
    const uint32_t* ab = area_bits + b * NBOXES;

    __shared__ uint64_t s_key[NPAD];     // 43.3 KB
    __shared__ int      s_pref[NPAD];    // 21.6 KB (also reused as start[] in area regime)
    __shared__ uint64_t s_sel[512];      // 4 KB
    __shared__ int      s_scan[512];     // 2 KB
    __shared__ int      s_hist[256];     // 1 KB
    __shared__ float    s_Ki[NCC][9];
    __shared__ uint64_t s_prefix;
    __shared__ int      s_need, s_done, s_cnt;

    if (tid < NCC) invert3x3(K + (b * NCC + tid) * 16, s_Ki[tid]);

    // ---- build keys + total count ----
    int partial = 0;
    for (int t = tid; t < NPAD; t += 512) {
        uint64_t key = 0;
        if (t < NBOXES) {
            uint64_t mk = mb[t];
            int cnt = __popcll(mk);
            partial += cnt;
            if (cnt) key = ((uint64_t)ab[t] << 32) |
                           ((uint64_t)(NPAD - 1 - t) << 6) | (uint64_t)cnt;
        }
        s_key[t] = key;
    }
    s_scan[tid] = partial;
    __syncthreads();
    for (int s = 256; s > 0; s >>= 1) {
        if (tid < s) s_scan[tid] += s_scan[tid + s];
        __syncthreads();
    }
    int total = s_scan[0];
    __syncthreads();
    int total_take = total < NQ ? total : NQ;

    if (total > NQ) {
        // ======== AREA REGIME ========
        if (tid == 0) { s_prefix = 0ull; s_need = NQ; s_done = 0; }
        __syncthreads();
        for (int shift = 56; shift >= 0; shift -= 8) {
            if (tid < 256) s_hist[tid] = 0;
            __syncthreads();
            uint64_t pref = s_prefix;
            for (int t = tid; t < NBOXES; t += 512) {
                uint64_t k = s_key[t];
                if (!k) continue;
                if (shift == 56 || (k >> (shift + 8)) == (pref >> (shift + 8)))
                    atomicAdd(&s_hist[(int)((k >> shift) & 255ull)], (int)(k & 63ull));
            }
            __syncthreads();
            if (tid == 0) {
                int need = s_need, cum = 0, dsel = 0;
                for (int dg = 255; dg >= 0; --dg) {
                    int hc = s_hist[dg];
                    if (cum + hc >= need) {
                        dsel = dg;
                        s_need = need - cum;
                        if (hc == need - cum) s_done = 1;
                        break;
                    }
                    cum += hc;
                }
                s_prefix = pref | ((uint64_t)dsel << shift);
            }
            __syncthreads();
            if (s_done) break;
        }
        uint64_t T = s_prefix;

        // compact boxes with key >= T (<= 400 of them, each weight >= 1)
        if (tid == 0) s_cnt = 0;
        __syncthreads();
        for (int t = tid; t < NBOXES; t += 512) {
            uint64_t k = s_key[t];
            if (k && k >= T) {
                int p = atomicAdd(&s_cnt, 1);
                if (p < 512) s_sel[p] = k;
            }
        }
        __syncthreads();
        int C = s_cnt;
        if (tid >= C) s_sel[tid] = 0ull;
        __syncthreads();

        // bitonic sort 512 ascending, one element per thread
        for (int kk = 2; kk <= 512; kk <<= 1) {
            for (int jj = kk >> 1; jj > 0; jj >>= 1) {
                int i = tid, ixj = i ^ jj;
                if (ixj > i) {
                    bool up = ((i & kk) == 0);
                    uint64_t av = s_sel[i], bv = s_sel[ixj];
                    if ((av > bv) == up) { s_sel[i] = bv; s_sel[ixj] = av; }
                }
                __syncthreads();
            }
        }

        // rank r (descending) lives at s_sel[511 - r]; scan counts
        uint64_t mykey = s_sel[511 - tid];
        int mycnt = (int)(mykey & 63ull);
        s_scan[tid] = mycnt;
        __syncthreads();
        for (int off = 1; off < 512; off <<= 1) {
            int v = (tid >= off) ? s_scan[tid - off] : 0;
            __syncthreads();
            s_scan[tid] += v;
            __syncthreads();
        }
        s_pref[tid] = mycnt ? (s_scan[tid] - mycnt) : 0x7FFFFFFF;
        __syncthreads();

        // emit
        const float denom = 102.4f + 1e-6f;
        for (int q = tid; q < NQ; q += 512) {
            float X = 0.0f, Y = 0.0f, Z = 0.0f, pm = 1.0f;
            if (q < total_take) {
                int lo = 0, hi = 511;
                while (lo < hi) {
                    int mid = (lo + hi + 1) >> 1;
                    if (s_pref[mid] <= q) lo = mid; else hi = mid - 1;
                }
                uint64_t k = s_sel[511 - lo];
                int cn = (NPAD - 1) - (int)((k >> 6) & 8191ull);
                int r  = q - s_pref[lo];
                uint64_t mask = mb[cn];
                for (int jj = 0; jj < r; ++jj) mask &= (mask - 1);
                int d = __builtin_ctzll(mask);
                int c = cn / NBOX;
                const float* bx = boxes + (b * NBOXES + cn) * 4;
                float x1 = bx[0], y1 = bx[1], x2 = bx[2], y2 = bx[3];
                float cx = (x1 + x2) * 0.5f, cy = (y1 + y2) * 0.5f;
                const float step = (60.0f - 1.0f) / 47.0f;
                float z = (d == ND - 1) ? 60.0f : 1.0f + (float)d * step;
                const float* Ki = s_Ki[c];
                float u0 = cx * z, u1 = cy * z;
                float pcx = Ki[0] * u0 + Ki[1] * u1 + Ki[2] * z;
                float pcy = Ki[3] * u0 + Ki[4] * u1 + Ki[5] * z;
                float pcz = Ki[6] * u0 + Ki[7] * u1 + Ki[8] * z;
                const float* Ep = E + (b * NCC + c) * 16;
                X = Ep[0] * pcx + Ep[1] * pcy + Ep[2]  * pcz + Ep[3];
                Y = Ep[4] * pcx + Ep[5] * pcy + Ep[6]  * pcz + Ep[7];
                Z = Ep[8] * pcx + Ep[9] * pcy + Ep[10] * pcz + Ep[11];
                pm = 0.0f;
            }
            float* o = out + (b * NQ + q) * 3;
            o[0] = fminf(fmaxf((X + 51.2f) / denom, 0.0f), 1.0f);
            o[1] = fminf(fmaxf((Y + 51.2f) / denom, 0.0f), 1.0f);
            o[2] = fminf(fmaxf((Z + 51.2f) / denom, 0.0f), 1.0f);
            out[REFSZ + b * NQ + q] = pm;
        }
    } else {
        // ======== ORDER REGIME ======== (boxes already in index order)
        // blocked exclusive prefix of per-box counts
        int base = tid * 11;
        int run = 0;
        for (int u = 0; u < 11; ++u) {
            int t = base + u;
            if (t < NBOXES) {
                s_pref[t] = run;
                run += (int)(s_key[t] & 63ull);
            }
        }
        s_scan[tid] = run;
        __syncthreads();
        for (int off = 1; off < 512; off <<= 1) {
            int v = (tid >= off) ? s_scan[tid - off] : 0;
            __syncthreads();
            s_scan[tid] += v;
            __syncthreads();
        }
        int toff = s_scan[tid] - run;
        for (int u = 0; u < 11; ++u) {
            int t = base + u;
            if (t < NBOXES) s_pref[t] += toff;
        }
        for (int t = NBOXES + tid; t < NPAD; t += 512) s_pref[t] = 0x7FFFFFFF;
        __syncthreads();

        const float denom = 102.4f + 1e-6f;
        for (int q = tid; q < NQ; q += 512) {
            float X = 0.0f, Y = 0.0f, Z = 0.0f, pm = 1.0f;
            if (q < total_take) {
                int lo = 0, hi = NPAD - 1;
                while (lo < hi) {
                    int mid = (lo + hi + 1) >> 1;
                    if (s_pref[mid] <= q) lo = mid; else hi = mid - 1;
                }
                int cn = lo;
                int r  = q - s_pref[lo];
                uint64_t mask = mb[cn];
                for (int jj = 0; jj < r; ++jj) mask &= (mask - 1);
                int d = __builtin_ctzll(mask);
                int c = cn / NBOX;
                const float* bx = boxes + (b * NBOXES + cn) * 4;
                float x1 = bx[0], y1 = bx[1], x2 = bx[2], y2 = bx[3];
                float cx = (x1 + x2) * 0.5f, cy = (y1 + y2) * 0.5f;
                const float step = (60.0f - 1.0f) / 47.0f;
                float z = (d == ND - 1) ? 60.0f : 1.0f + (float)d * step;
                const float* Ki = s_Ki[c];
                float u0 = cx * z, u1 = cy * z;
                float pcx = Ki[0] * u0 + Ki[1] * u1 + Ki[2] * z;
                float pcy = Ki[3] * u0 + Ki[4] * u1 + Ki[5] * z;
                float pcz = Ki[6] * u0 + Ki[7] * u1 + Ki[8] * z;
                const float* Ep = E + (b * NCC + c) * 16;
                X = Ep[0] * pcx + Ep[1] * pcy + Ep[2]  * pcz + Ep[3];
                Y = Ep[4] * pcx + Ep[5] * pcy + Ep[6]  * pcz + Ep[7];
                Z = Ep[8] * pcx + Ep[9] * pcy + Ep[10] * pcz + Ep[11];
                pm = 0.0f;
            }
            float* o = out + (b * NQ + q) * 3;
            o[0] = fminf(fmaxf((X + 51.2f) / denom, 0.0f), 1.0f);
            o[1] = fminf(fmaxf((Y + 51.2f) / denom, 0.0f), 1.0f);
            o[2] = fminf(fmaxf((Z + 51.2f) / denom, 0.0f), 1.0f);
            out[REFSZ + b * NQ + q] = pm;
        }
    }
}

extern "C" void kernel_launch(void* const* d_in, const int* in_sizes, int n_in,
                              void* d_out, int out_size, void* d_ws, size_t ws_size,
                              hipStream_t stream) {
    const float* boxes = (const float*)d_in[0];
    const float* K     = (const float*)d_in[1];
    const float* E     = (const float*)d_in[2];
    // ws layout: [0, 345600) mask64 (8*5400 u64) | [345600, 518400) area_bits (8*5400 u32)
    uint64_t* mask64    = (uint64_t*)d_ws;
    uint32_t* area_bits = (uint32_t*)((char*)d_ws + 345600);
    float*    out       = (float*)d_out;

    int nthreads = BB * NBOXES * TPB_BOX;   // 259200
    mask_kernel<<<(nthreads + 255) / 256, 256, 0, stream>>>(
        boxes, K, E, (uint8_t*)mask64, area_bits);
    select_kernel<<<BB, 512, 0, stream>>>(mask64, area_bits, boxes, K, E, out);
}

// Round 4
// 105.905 us; speedup vs baseline: 16.1480x; 2.2293x over previous
//
#include <hip/hip_runtime.h>
#include <math.h>
#include <stdint.h>

#define BB 8
#define NCC 6
#define NBOX 900
#define NBOXES (NCC * NBOX)      // 5400 boxes per batch
#define NBC (BB * NCC)           // 48 cameras
#define ND 48
#define TPB_BOX 6                // threads per box in mask kernel (8 depths each)
#define NQ 400
#define REFSZ (BB * NQ * 3)
#define NPAD 5408

// nan_to_num applied to an f32-rounded double (matches ref's _nan_to_num on the f32 inverse)
__device__ __forceinline__ float nnf(double x) {
    float v = (float)x;
    if (isnan(v)) return 0.0f;
    if (isinf(v)) return v > 0.0f ? 1e6f : -1e6f;
    return v;
}

__device__ void invert3x3(const float* __restrict__ Kp, float* __restrict__ Ki) {
    double a00 = Kp[0], a01 = Kp[1], a02 = Kp[2];
    double a10 = Kp[4], a11 = Kp[5], a12 = Kp[6];
    double a20 = Kp[8], a21 = Kp[9], a22 = Kp[10];
    double c00 = a11 * a22 - a12 * a21;
    double c10 = a12 * a20 - a10 * a22;
    double c20 = a10 * a21 - a11 * a20;
    double det = a00 * c00 + a01 * c10 + a02 * c20;
    double id  = 1.0 / det;
    Ki[0] = nnf(c00 * id); Ki[1] = nnf((a02 * a21 - a01 * a22) * id); Ki[2] = nnf((a01 * a12 - a02 * a11) * id);
    Ki[3] = nnf(c10 * id); Ki[4] = nnf((a00 * a22 - a02 * a20) * id); Ki[5] = nnf((a02 * a10 - a00 * a12) * id);
    Ki[6] = nnf(c20 * id); Ki[7] = nnf((a01 * a20 - a00 * a21) * id); Ki[8] = nnf((a00 * a11 - a01 * a10) * id);
}

__device__ void invert4x4(const float* __restrict__ Ep, float* __restrict__ Ei) {
    double m[4][8];
    for (int i = 0; i < 4; ++i)
        for (int j = 0; j < 4; ++j) {
            m[i][j]     = (double)Ep[i * 4 + j];
            m[i][4 + j] = (i == j) ? 1.0 : 0.0;
        }
    for (int col = 0; col < 4; ++col) {
        int piv = col; double best = fabs(m[col][col]);
        for (int r = col + 1; r < 4; ++r) {
            double v = fabs(m[r][col]);
            if (v > best) { best = v; piv = r; }
        }
        if (piv != col)
            for (int j = 0; j < 8; ++j) { double tmp = m[col][j]; m[col][j] = m[piv][j]; m[piv][j] = tmp; }
        double ipv = 1.0 / m[col][col];
        for (int j = 0; j < 8; ++j) m[col][j] *= ipv;
        for (int r = 0; r < 4; ++r) {
            if (r == col) continue;
            double f = m[r][col];
            if (f != 0.0)
                for (int j = 0; j < 8; ++j) m[r][j] -= f * m[col][j];
        }
    }
    for (int i = 0; i < 16; ++i) Ei[i] = nnf(m[i / 4][4 + (i & 3)]);
}

// ---------------- kernel 1: per-(box, j) mask over 8 depths ----------------
__global__ __launch_bounds__(256) void mask_kernel(const float* __restrict__ boxes,
                                                   const float* __restrict__ K,
                                                   const float* __restrict__ E,
                                                   uint8_t* __restrict__ mask_bytes,
                                                   uint32_t* __restrict__ area_bits) {
    __shared__ float sKi[2][9];
    __shared__ float sEv[2][16];

    int gbase = blockIdx.x * 256;
    int bc_lo = gbase / (NBOX * TPB_BOX);
    int bc_hi = (gbase + 255) / (NBOX * TPB_BOX);
    if (bc_hi > NBC - 1) bc_hi = NBC - 1;
    if (threadIdx.x == 0) {
        invert3x3(K + bc_lo * 16, sKi[0]);
        invert4x4(E + bc_lo * 16, sEv[0]);
    }
    if (threadIdx.x == 1 && bc_hi != bc_lo) {
        invert3x3(K + bc_hi * 16, sKi[1]);
        invert4x4(E + bc_hi * 16, sEv[1]);
    }
    __syncthreads();

    int gtid = gbase + threadIdx.x;
    if (gtid >= BB * NBOXES * TPB_BOX) return;
    int box = gtid / TPB_BOX;
    int j   = gtid - box * TPB_BOX;
    int bc  = box / NBOX;

    const float* bx = boxes + box * 4;
    float x1 = bx[0], y1 = bx[1], x2 = bx[2], y2 = bx[3];
    float area  = (x2 - x1) * (y2 - y1);
    bool  valid = (area > 5.0f) && (area < 197120.0f);
    if (j == 0) {
        area_bits[box] = __float_as_uint(area);
        *(uint16_t*)(mask_bytes + box * 8 + 6) = 0;
    }

    uint32_t m8 = 0;
    if (valid) {
        int sel = (bc == bc_lo) ? 0 : 1;
        float Ki[9], Ev[16], Ep[12], Kp[11];
        #pragma unroll
        for (int i = 0; i < 9; ++i)  Ki[i] = sKi[sel][i];
        #pragma unroll
        for (int i = 0; i < 16; ++i) Ev[i] = sEv[sel][i];
        const float* Epp = E + bc * 16;
        #pragma unroll
        for (int i = 0; i < 12; ++i) Ep[i] = Epp[i];
        const float* Kpp = K + bc * 16;
        #pragma unroll
        for (int i = 0; i < 11; ++i) Kp[i] = Kpp[i];

        float cx = (x1 + x2) * 0.5f, cy = (y1 + y2) * 0.5f;
        const float step = (60.0f - 1.0f) / 47.0f;

        #pragma unroll
        for (int dd = 0; dd < 8; ++dd) {
            int d = j * 8 + dd;
            float z = (d == ND - 1) ? 60.0f : 1.0f + (float)d * step;
            float u0 = cx * z, u1 = cy * z;
            float pcx = Ki[0] * u0 + Ki[1] * u1 + Ki[2] * z;
            float pcy = Ki[3] * u0 + Ki[4] * u1 + Ki[5] * z;
            float pcz = Ki[6] * u0 + Ki[7] * u1 + Ki[8] * z;

            float X = Ep[0] * pcx + Ep[1] * pcy + Ep[2]  * pcz + Ep[3];
            float Y = Ep[4] * pcx + Ep[5] * pcy + Ep[6]  * pcz + Ep[7];
            float Z = Ep[8] * pcx + Ep[9] * pcy + Ep[10] * pcz + Ep[11];

            float q0 = Ev[0]  * X + Ev[1]  * Y + Ev[2]  * Z + Ev[3];
            float q1 = Ev[4]  * X + Ev[5]  * Y + Ev[6]  * Z + Ev[7];
            float q2 = Ev[8]  * X + Ev[9]  * Y + Ev[10] * Z + Ev[11];
            float q3 = Ev[12] * X + Ev[13] * Y + Ev[14] * Z + Ev[15];
            float w  = q3 + 1e-6f;
            float r0 = q0 / w, r1 = q1 / w, r2 = q2 / w;

            float p0 = Kp[0] * r0 + Kp[1] * r1 + Kp[2]  * r2;
            float p1 = Kp[4] * r0 + Kp[5] * r1 + Kp[6]  * r2;
            float p2 = Kp[8] * r0 + Kp[9] * r1 + Kp[10] * r2;
            float iz = p2 + 1e-6f;
            float ix = p0 / iz, iy = p1 / iz;

            float bs = 40.0f * (10.0f / (r2 + 1e-6f));
            bs = fminf(fmaxf(bs, 8.0f), 200.0f);
            float hh = bs / 2.0f;
            float px1 = ix - hh, py1 = iy - hh, px2 = ix + hh, py2 = iy + hh;

            float ix1 = fmaxf(px1, x1), iy1 = fmaxf(py1, y1);
            float ix2 = fminf(px2, x2), iy2 = fminf(py2, y2);
            float inter = fmaxf(ix2 - ix1, 0.0f) * fmaxf(iy2 - iy1, 0.0f);
            float a1 = (px2 - px1) * (py2 - py1);
            float iou = inter / (a1 + area - inter + 1e-6f);

            if (iou > 0.05f) m8 |= (1u << dd);
        }
    }
    mask_bytes[box * 8 + j] = (uint8_t)m8;
}

// ---------------- kernel 2: per-batch top-400 select + output ----------------
// Box key: (area_bits << 32) | (inv_box << 6) | cnt  (distinct, nonzero iff cnt>0).
// Area regime: weighted radix-select with PARALLEL per-pass boundary-digit
// search (wave-0 shuffle suffix-scan over 256 bins), compact survivors,
// per-thread weighted rank (broadcast LDS reads, no sort, no barriers),
// scatter (box,depth) into a 400-slot table, direct-lookup emit.
// Order regime: blocked prefix of counts, scatter, direct-lookup emit.
__global__ __launch_bounds__(512) void select_kernel(const uint64_t* __restrict__ mask64,
                                                     const uint32_t* __restrict__ area_bits,
                                                     const float* __restrict__ boxes,
                                                     const float* __restrict__ K,
                                                     const float* __restrict__ E,
                                                     float* __restrict__ out) {
    int b   = blockIdx.x;
    int tid = threadIdx.x;
    const uint64_t* mb = mask64 + b * NBOXES;
    const uint32_t* ab = area_bits + b * NBOXES;

    __shared__ uint64_t s_key[NPAD];     // 43.3 KB
    __shared__ uint64_t s_sel[512];      // 4 KB
    __shared__ int      s_out[NQ];       // 1.6 KB  packed (cn<<6)|d, -1 = pad
    __shared__ int      s_hist[256];
    __shared__ int      s_scan[512];
    __shared__ float    s_Ki[NCC][9];
    __shared__ uint64_t s_prefix;
    __shared__ int      s_need, s_done, s_cnt;

    if (tid < NCC) invert3x3(K + (b * NCC + tid) * 16, s_Ki[tid]);
    if (tid < NQ) s_out[tid] = -1;

    // ---- build keys + total count ----
    int partial = 0;
    for (int t = tid; t < NPAD; t += 512) {
        uint64_t key = 0;
        if (t < NBOXES) {
            uint64_t mk = mb[t];
            int cnt = __popcll(mk);
            partial += cnt;
            if (cnt) key = ((uint64_t)ab[t] << 32) |
                           ((uint64_t)(NPAD - 1 - t) << 6) | (uint64_t)cnt;
        }
        s_key[t] = key;
    }
    s_scan[tid] = partial;
    __syncthreads();
    for (int s = 256; s > 0; s >>= 1) {
        if (tid < s) s_scan[tid] += s_scan[tid + s];
        __syncthreads();
    }
    int total = s_scan[0];
    __syncthreads();

    if (total > NQ) {
        // ======== AREA REGIME ========
        if (tid == 0) { s_prefix = 0ull; s_need = NQ; s_done = 0; }
        __syncthreads();
        for (int shift = 56; shift >= 0; shift -= 8) {
            if (tid < 256) s_hist[tid] = 0;
            __syncthreads();
            uint64_t pref = s_prefix;
            for (int t = tid; t < NBOXES; t += 512) {
                uint64_t k = s_key[t];
                if (!k) continue;
                if (shift == 56 || (k >> (shift + 8)) == (pref >> (shift + 8)))
                    atomicAdd(&s_hist[(int)((k >> shift) & 255ull)], (int)(k & 63ull));
            }
            __syncthreads();
            if (tid < 64) {
                // lane owns bins 4t..4t+3; suffix sums via shuffle (no barriers)
                int h0 = s_hist[4 * tid + 0], h1 = s_hist[4 * tid + 1];
                int h2 = s_hist[4 * tid + 2], h3 = s_hist[4 * tid + 3];
                int lanesum = h0 + h1 + h2 + h3;
                int sufinc = lanesum;
                #pragma unroll
                for (int off = 1; off < 64; off <<= 1) {
                    int v = __shfl_down(sufinc, off);
                    if (tid + off < 64) sufinc += v;
                }
                int above = sufinc - lanesum;           // strictly-higher lanes
                int need  = s_need;
                // C(dg) inclusive-from-top; Cnext = C(dg+1); unique crossing
                int C3 = above + h3;
                int C2 = C3 + h2;
                int C1 = C2 + h1;
                int C0 = C1 + h0;
                int dg = -1, hc = 0, Cnext = 0;
                if (C3 >= need && above < need) { dg = 4 * tid + 3; hc = h3; Cnext = above; }
                else if (C2 >= need && C3 < need) { dg = 4 * tid + 2; hc = h2; Cnext = C3; }
                else if (C1 >= need && C2 < need) { dg = 4 * tid + 1; hc = h1; Cnext = C2; }
                else if (C0 >= need && C1 < need) { dg = 4 * tid + 0; hc = h0; Cnext = C1; }
                if (dg >= 0) {
                    s_prefix = pref | ((uint64_t)dg << shift);
                    s_need   = need - Cnext;
                    if (hc == need - Cnext) s_done = 1;
                }
            }
            __syncthreads();
            if (s_done) break;
        }
        uint64_t T = s_prefix;

        // compact survivors (<= ~447 boxes: weight(>T) < 400, boundary box <= 48)
        if (tid == 0) s_cnt = 0;
        __syncthreads();
        for (int t = tid; t < NBOXES; t += 512) {
            uint64_t k = s_key[t];
            if (k && k >= T) {
                int p = atomicAdd(&s_cnt, 1);
                if (p < 512) s_sel[p] = k;
            }
        }
        __syncthreads();
        int C = s_cnt;
        if (C > 512) C = 512;

        // weighted rank (keys distinct) + scatter depths
        if (tid < C) {
            uint64_t k = s_sel[tid];
            int w = (int)(k & 63ull);
            int start = 0;
            for (int j = 0; j < C; ++j) {
                uint64_t kj = s_sel[j];               // broadcast read
                if (kj > k) start += (int)(kj & 63ull);
            }
            int cn = (NPAD - 1) - (int)((k >> 6) & 8191ull);
            uint64_t mask = mb[cn];
            for (int i = 0; i < w; ++i) {
                int d = __builtin_ctzll(mask);
                mask &= (mask - 1);
                int pos = start + i;
                if (pos < NQ) s_out[pos] = (cn << 6) | d;
            }
        }
        __syncthreads();
    } else {
        // ======== ORDER REGIME ======== (boxes already in index order)
        int base = tid * 11;
        int run = 0;
        for (int u = 0; u < 11; ++u) {
            int t = base + u;
            if (t < NBOXES) run += (int)(s_key[t] & 63ull);
        }
        s_scan[tid] = run;
        __syncthreads();
        for (int off = 1; off < 512; off <<= 1) {
            int v = (tid >= off) ? s_scan[tid - off] : 0;
            __syncthreads();
            s_scan[tid] += v;
            __syncthreads();
        }
        int pos = s_scan[tid] - run;                  // exclusive offset of my range
        for (int u = 0; u < 11; ++u) {
            int t = base + u;
            if (t >= NBOXES) break;
            uint64_t k = s_key[t];
            if (!k) continue;
            int w = (int)(k & 63ull);
            uint64_t mask = mb[t];
            for (int i = 0; i < w; ++i) {
                int d = __builtin_ctzll(mask);
                mask &= (mask - 1);
                if (pos < NQ) s_out[pos] = (t << 6) | d;
                ++pos;
            }
        }
        __syncthreads();
    }

    // ---- emit: direct lookup ----
    const float denom = 102.4f + 1e-6f;
    if (tid < NQ) {
        int v = s_out[tid];
        float X = 0.0f, Y = 0.0f, Z = 0.0f, pm = 1.0f;
        if (v >= 0) {
            int cn = v >> 6;
            int d  = v & 63;
            int c  = cn / NBOX;
            const float* bx = boxes + (b * NBOXES + cn) * 4;
            float x1 = bx[0], y1 = bx[1], x2 = bx[2], y2 = bx[3];
            float cx = (x1 + x2) * 0.5f, cy = (y1 + y2) * 0.5f;
            const float step = (60.0f - 1.0f) / 47.0f;
            float z = (d == ND - 1) ? 60.0f : 1.0f + (float)d * step;
            const float* Ki = s_Ki[c];
            float u0 = cx * z, u1 = cy * z;
            float pcx = Ki[0] * u0 + Ki[1] * u1 + Ki[2] * z;
            float pcy = Ki[3] * u0 + Ki[4] * u1 + Ki[5] * z;
            float pcz = Ki[6] * u0 + Ki[7] * u1 + Ki[8] * z;
            const float* Ep = E + (b * NCC + c) * 16;
            X = Ep[0] * pcx + Ep[1] * pcy + Ep[2]  * pcz + Ep[3];
            Y = Ep[4] * pcx + Ep[5] * pcy + Ep[6]  * pcz + Ep[7];
            Z = Ep[8] * pcx + Ep[9] * pcy + Ep[10] * pcz + Ep[11];
            pm = 0.0f;
        }
        float* o = out + (b * NQ + tid) * 3;
        o[0] = fminf(fmaxf((X + 51.2f) / denom, 0.0f), 1.0f);
        o[1] = fminf(fmaxf((Y + 51.2f) / denom, 0.0f), 1.0f);
        o[2] = fminf(fmaxf((Z + 51.2f) / denom, 0.0f), 1.0f);
        out[REFSZ + b * NQ + tid] = pm;
    }
}

extern "C" void kernel_launch(void* const* d_in, const int* in_sizes, int n_in,
                              void* d_out, int out_size, void* d_ws, size_t ws_size,
                              hipStream_t stream) {
    const float* boxes = (const float*)d_in[0];
    const float* K     = (const float*)d_in[1];
    const float* E     = (const float*)d_in[2];
    uint64_t* mask64    = (uint64_t*)d_ws;
    uint32_t* area_bits = (uint32_t*)((char*)d_ws + 345600);
    float*    out       = (float*)d_out;

    int nthreads = BB * NBOXES * TPB_BOX;   // 259200
    mask_kernel<<<(nthreads + 255) / 256, 256, 0, stream>>>(
        boxes, K, E, (uint8_t*)mask64, area_bits);
    select_kernel<<<BB, 512, 0, stream>>>(mask64, area_bits, boxes, K, E, out);
}